// Round 1
// baseline (45.570 us; speedup 1.0000x reference)
//
#include <hip/hip_runtime.h>
#include <math.h>

#define HID 2048
#define EMB 512
#define NV 16

__device__ __forceinline__ float wred(float v) {
#pragma unroll
    for (int o = 32; o >= 1; o >>= 1) v += __shfl_down(v, o, 64);
    return v;
}

__device__ __forceinline__ float sig(float x) { return 1.0f / (1.0f + __expf(-x)); }

// k1: computes h0 (blocks 0..2047) and gh1 = w_hh1 @ h_in[1] + b_hh1 (blocks 2048..4095)
__global__ __launch_bounds__(256) void k1(
    const int* __restrict__ xidx,
    const float* __restrict__ h_in,
    const float* __restrict__ emb,
    const float* __restrict__ w_ih0,
    const float* __restrict__ w_hh0,
    const float* __restrict__ b_ih0,
    const float* __restrict__ b_hh0,
    const float* __restrict__ w_hh1,
    const float* __restrict__ b_hh1,
    float* __restrict__ out,
    float* __restrict__ gh1)
{
    const int tid  = threadIdx.x;
    const int lane = tid & 63;
    const int wv   = tid >> 6;
    const int bid  = blockIdx.x;
    __shared__ float red[4][6];

    float s0 = 0.f, s1 = 0.f, s2 = 0.f, s3 = 0.f, s4 = 0.f, s5 = 0.f;

    if (bid < HID) {
        const int j = bid;
        const float4* ev  = (const float4*)(emb + (size_t)xidx[0] * EMB);
        const float4* hv  = (const float4*)h_in;                      // h_in[0]
        const float4* wi0 = (const float4*)(w_ih0 + (size_t)j * EMB);
        const float4* wi1 = (const float4*)(w_ih0 + (size_t)(j + HID) * EMB);
        const float4* wi2 = (const float4*)(w_ih0 + (size_t)(j + 2 * HID) * EMB);
        if (tid < EMB / 4) {
            float4 x = ev[tid];
            float4 a = wi0[tid]; s0 = a.x * x.x + a.y * x.y + a.z * x.z + a.w * x.w;
            float4 b = wi1[tid]; s1 = b.x * x.x + b.y * x.y + b.z * x.z + b.w * x.w;
            float4 c = wi2[tid]; s2 = c.x * x.x + c.y * x.y + c.z * x.z + c.w * x.w;
        }
        const float4* wh0 = (const float4*)(w_hh0 + (size_t)j * HID);
        const float4* wh1 = (const float4*)(w_hh0 + (size_t)(j + HID) * HID);
        const float4* wh2 = (const float4*)(w_hh0 + (size_t)(j + 2 * HID) * HID);
        for (int c = tid; c < HID / 4; c += 256) {
            float4 x = hv[c];
            float4 a = wh0[c]; s3 += a.x * x.x + a.y * x.y + a.z * x.z + a.w * x.w;
            float4 b = wh1[c]; s4 += b.x * x.x + b.y * x.y + b.z * x.z + b.w * x.w;
            float4 d = wh2[c]; s5 += d.x * x.x + d.y * x.y + d.z * x.z + d.w * x.w;
        }
    } else {
        const int j = bid - HID;
        const float4* hv  = (const float4*)(h_in + HID);              // h_in[1]
        const float4* wh0 = (const float4*)(w_hh1 + (size_t)j * HID);
        const float4* wh1 = (const float4*)(w_hh1 + (size_t)(j + HID) * HID);
        const float4* wh2 = (const float4*)(w_hh1 + (size_t)(j + 2 * HID) * HID);
        for (int c = tid; c < HID / 4; c += 256) {
            float4 x = hv[c];
            float4 a = wh0[c]; s0 += a.x * x.x + a.y * x.y + a.z * x.z + a.w * x.w;
            float4 b = wh1[c]; s1 += b.x * x.x + b.y * x.y + b.z * x.z + b.w * x.w;
            float4 d = wh2[c]; s2 += d.x * x.x + d.y * x.y + d.z * x.z + d.w * x.w;
        }
    }

    s0 = wred(s0); s1 = wred(s1); s2 = wred(s2);
    s3 = wred(s3); s4 = wred(s4); s5 = wred(s5);
    if (lane == 0) {
        red[wv][0] = s0; red[wv][1] = s1; red[wv][2] = s2;
        red[wv][3] = s3; red[wv][4] = s4; red[wv][5] = s5;
    }
    __syncthreads();
    if (tid == 0) {
        float t0 = red[0][0] + red[1][0] + red[2][0] + red[3][0];
        float t1 = red[0][1] + red[1][1] + red[2][1] + red[3][1];
        float t2 = red[0][2] + red[1][2] + red[2][2] + red[3][2];
        if (bid < HID) {
            const int j = bid;
            float t3 = red[0][3] + red[1][3] + red[2][3] + red[3][3];
            float t4 = red[0][4] + red[1][4] + red[2][4] + red[3][4];
            float t5 = red[0][5] + red[1][5] + red[2][5] + red[3][5];
            float ir  = t0 + b_ih0[j];
            float iz  = t1 + b_ih0[j + HID];
            float inn = t2 + b_ih0[j + 2 * HID];
            float hr  = t3 + b_hh0[j];
            float hz  = t4 + b_hh0[j + HID];
            float hn  = t5 + b_hh0[j + 2 * HID];
            float r = sig(ir + hr);
            float z = sig(iz + hz);
            float n = tanhf(inn + r * hn);
            out[NV + j] = (1.0f - z) * n + z * h_in[j];
        } else {
            const int j = bid - HID;
            gh1[j]           = t0 + b_hh1[j];
            gh1[j + HID]     = t1 + b_hh1[j + HID];
            gh1[j + 2 * HID] = t2 + b_hh1[j + 2 * HID];
        }
    }
}

// k2: gi1 = w_ih1 @ h0 + b_ih1; combine with gh1 -> h1
__global__ __launch_bounds__(256) void k2(
    const float* __restrict__ h_in,
    const float* __restrict__ w_ih1,
    const float* __restrict__ b_ih1,
    const float* __restrict__ gh1,
    float* __restrict__ out)
{
    const int tid  = threadIdx.x;
    const int lane = tid & 63;
    const int wv   = tid >> 6;
    const int j    = blockIdx.x;
    __shared__ float red[4][3];

    const float4* hv  = (const float4*)(out + NV);                    // h0 from k1
    const float4* wi0 = (const float4*)(w_ih1 + (size_t)j * HID);
    const float4* wi1 = (const float4*)(w_ih1 + (size_t)(j + HID) * HID);
    const float4* wi2 = (const float4*)(w_ih1 + (size_t)(j + 2 * HID) * HID);

    float s0 = 0.f, s1 = 0.f, s2 = 0.f;
    for (int c = tid; c < HID / 4; c += 256) {
        float4 x = hv[c];
        float4 a = wi0[c]; s0 += a.x * x.x + a.y * x.y + a.z * x.z + a.w * x.w;
        float4 b = wi1[c]; s1 += b.x * x.x + b.y * x.y + b.z * x.z + b.w * x.w;
        float4 d = wi2[c]; s2 += d.x * x.x + d.y * x.y + d.z * x.z + d.w * x.w;
    }
    s0 = wred(s0); s1 = wred(s1); s2 = wred(s2);
    if (lane == 0) { red[wv][0] = s0; red[wv][1] = s1; red[wv][2] = s2; }
    __syncthreads();
    if (tid == 0) {
        float t0 = red[0][0] + red[1][0] + red[2][0] + red[3][0];
        float t1 = red[0][1] + red[1][1] + red[2][1] + red[3][1];
        float t2 = red[0][2] + red[1][2] + red[2][2] + red[3][2];
        float ir  = t0 + b_ih1[j];
        float iz  = t1 + b_ih1[j + HID];
        float inn = t2 + b_ih1[j + 2 * HID];
        float r = sig(ir + gh1[j]);
        float z = sig(iz + gh1[j + HID]);
        float n = tanhf(inn + r * gh1[j + 2 * HID]);
        out[NV + HID + j] = (1.0f - z) * n + z * h_in[HID + j];
    }
}

// k3: logits = w_head @ h1 + b_head; softmax -> probs
__global__ __launch_bounds__(256) void k3(
    const float* __restrict__ w_head,
    const float* __restrict__ b_head,
    float* __restrict__ out)
{
    const int tid = threadIdx.x;
    const int row = tid >> 4;   // 0..15
    const int sub = tid & 15;
    const float4* hv = (const float4*)(out + NV + HID);               // h1 from k2
    const float4* w  = (const float4*)(w_head + (size_t)row * HID);

    float s = 0.f;
    for (int c = sub; c < HID / 4; c += 16) {
        float4 x = hv[c];
        float4 a = w[c];
        s += a.x * x.x + a.y * x.y + a.z * x.z + a.w * x.w;
    }
#pragma unroll
    for (int o = 8; o >= 1; o >>= 1) s += __shfl_down(s, o, 16);

    __shared__ float logits[NV];
    if (sub == 0) logits[row] = s + b_head[row];
    __syncthreads();
    if (tid == 0) {
        float m = logits[0];
#pragma unroll
        for (int i = 1; i < NV; ++i) m = fmaxf(m, logits[i]);
        float ex[NV]; float den = 0.f;
#pragma unroll
        for (int i = 0; i < NV; ++i) { ex[i] = __expf(logits[i] - m); den += ex[i]; }
        float inv = 1.0f / den;
#pragma unroll
        for (int i = 0; i < NV; ++i) out[i] = ex[i] * inv;
    }
}

extern "C" void kernel_launch(void* const* d_in, const int* in_sizes, int n_in,
                              void* d_out, int out_size, void* d_ws, size_t ws_size,
                              hipStream_t stream) {
    const int*   x      = (const int*)  d_in[0];
    const float* h_in   = (const float*)d_in[1];
    const float* emb    = (const float*)d_in[2];
    const float* w_ih0  = (const float*)d_in[3];
    const float* w_hh0  = (const float*)d_in[4];
    const float* b_ih0  = (const float*)d_in[5];
    const float* b_hh0  = (const float*)d_in[6];
    const float* w_ih1  = (const float*)d_in[7];
    const float* w_hh1  = (const float*)d_in[8];
    const float* b_ih1  = (const float*)d_in[9];
    const float* b_hh1  = (const float*)d_in[10];
    const float* w_head = (const float*)d_in[11];
    const float* b_head = (const float*)d_in[12];
    float* out = (float*)d_out;
    float* gh1 = (float*)d_ws;  // 6144 floats

    k1<<<2 * HID, 256, 0, stream>>>(x, h_in, emb, w_ih0, w_hh0, b_ih0, b_hh0,
                                    w_hh1, b_hh1, out, gh1);
    k2<<<HID, 256, 0, stream>>>(h_in, w_ih1, b_ih1, gh1, out);
    k3<<<1, 256, 0, stream>>>(w_head, b_head, out);
}

// Round 2
// 36.762 us; speedup vs baseline: 1.2396x; 1.2396x over previous
//
#include <hip/hip_runtime.h>
#include <math.h>

#define HID 2048
#define EMB 512
#define NV 16

__device__ __forceinline__ float wred(float v) {
#pragma unroll
    for (int o = 32; o >= 1; o >>= 1) v += __shfl_down(v, o, 64);
    return v;
}

__device__ __forceinline__ float dot4(float4 a, float4 b) {
    return a.x * b.x + a.y * b.y + a.z * b.z + a.w * b.w;
}

__device__ __forceinline__ float sig(float x) { return 1.0f / (1.0f + __expf(-x)); }

// k1: computes h0 (blocks 0..2047) and gh1 = w_hh1 @ h_in[1] + b_hh1 (blocks 2048..4095)
__global__ __launch_bounds__(256) void k1(
    const int* __restrict__ xidx,
    const float* __restrict__ h_in,
    const float* __restrict__ emb,
    const float* __restrict__ w_ih0,
    const float* __restrict__ w_hh0,
    const float* __restrict__ b_ih0,
    const float* __restrict__ b_hh0,
    const float* __restrict__ w_hh1,
    const float* __restrict__ b_hh1,
    float* __restrict__ out,
    float* __restrict__ gh1)
{
    const int tid  = threadIdx.x;
    const int lane = tid & 63;
    const int wv   = tid >> 6;
    const int bid  = blockIdx.x;
    __shared__ float red[4][6];

    float s0 = 0.f, s1 = 0.f, s2 = 0.f, s3 = 0.f, s4 = 0.f, s5 = 0.f;

    if (bid < HID) {
        const int j = bid;
        // prefetch epilogue scalars early (uniform broadcast loads)
        const float bi_r = b_ih0[j];
        const float bi_z = b_ih0[j + HID];
        const float bi_n = b_ih0[j + 2 * HID];
        const float bh_r = b_hh0[j];
        const float bh_z = b_hh0[j + HID];
        const float bh_n = b_hh0[j + 2 * HID];
        const float hprev = h_in[j];

        const float4* hv  = (const float4*)h_in;                      // h_in[0]
        const float4* wh0 = (const float4*)(w_hh0 + (size_t)j * HID);
        const float4* wh1 = (const float4*)(w_hh0 + (size_t)(j + HID) * HID);
        const float4* wh2 = (const float4*)(w_hh0 + (size_t)(j + 2 * HID) * HID);

        // batch-issue all hh loads (8 independent float4 loads in flight)
        float4 x0 = hv[tid];
        float4 x1 = hv[tid + 256];
        float4 a0 = wh0[tid];
        float4 a1 = wh0[tid + 256];
        float4 b0 = wh1[tid];
        float4 b1 = wh1[tid + 256];
        float4 d0 = wh2[tid];
        float4 d1 = wh2[tid + 256];

        // ih part: 128 float4 per row, threads 0..127 (4 more loads in flight)
        if (tid < 128) {
            const float4* ev  = (const float4*)(emb + (size_t)xidx[0] * EMB);
            const float4* wi0 = (const float4*)(w_ih0 + (size_t)j * EMB);
            const float4* wi1 = (const float4*)(w_ih0 + (size_t)(j + HID) * EMB);
            const float4* wi2 = (const float4*)(w_ih0 + (size_t)(j + 2 * HID) * EMB);
            float4 e4 = ev[tid];
            float4 ia = wi0[tid];
            float4 ib = wi1[tid];
            float4 ic = wi2[tid];
            s0 = dot4(ia, e4);
            s1 = dot4(ib, e4);
            s2 = dot4(ic, e4);
        }

        s3 = dot4(a0, x0) + dot4(a1, x1);
        s4 = dot4(b0, x0) + dot4(b1, x1);
        s5 = dot4(d0, x0) + dot4(d1, x1);

        s0 = wred(s0); s1 = wred(s1); s2 = wred(s2);
        s3 = wred(s3); s4 = wred(s4); s5 = wred(s5);
        if (lane == 0) {
            red[wv][0] = s0; red[wv][1] = s1; red[wv][2] = s2;
            red[wv][3] = s3; red[wv][4] = s4; red[wv][5] = s5;
        }
        __syncthreads();
        if (tid == 0) {
            float ir  = red[0][0] + red[1][0] + red[2][0] + red[3][0] + bi_r;
            float iz  = red[0][1] + red[1][1] + red[2][1] + red[3][1] + bi_z;
            float inn = red[0][2] + red[1][2] + red[2][2] + red[3][2] + bi_n;
            float hr  = red[0][3] + red[1][3] + red[2][3] + red[3][3] + bh_r;
            float hz  = red[0][4] + red[1][4] + red[2][4] + red[3][4] + bh_z;
            float hn  = red[0][5] + red[1][5] + red[2][5] + red[3][5] + bh_n;
            float r = sig(ir + hr);
            float z = sig(iz + hz);
            float n = tanhf(inn + r * hn);
            out[NV + j] = (1.0f - z) * n + z * hprev;
        }
    } else {
        const int j = bid - HID;
        const float bh_r = b_hh1[j];
        const float bh_z = b_hh1[j + HID];
        const float bh_n = b_hh1[j + 2 * HID];

        const float4* hv  = (const float4*)(h_in + HID);              // h_in[1]
        const float4* wh0 = (const float4*)(w_hh1 + (size_t)j * HID);
        const float4* wh1 = (const float4*)(w_hh1 + (size_t)(j + HID) * HID);
        const float4* wh2 = (const float4*)(w_hh1 + (size_t)(j + 2 * HID) * HID);

        float4 x0 = hv[tid];
        float4 x1 = hv[tid + 256];
        float4 a0 = wh0[tid];
        float4 a1 = wh0[tid + 256];
        float4 b0 = wh1[tid];
        float4 b1 = wh1[tid + 256];
        float4 d0 = wh2[tid];
        float4 d1 = wh2[tid + 256];

        s0 = dot4(a0, x0) + dot4(a1, x1);
        s1 = dot4(b0, x0) + dot4(b1, x1);
        s2 = dot4(d0, x0) + dot4(d1, x1);

        s0 = wred(s0); s1 = wred(s1); s2 = wred(s2);
        if (lane == 0) {
            red[wv][0] = s0; red[wv][1] = s1; red[wv][2] = s2;
        }
        __syncthreads();
        if (tid == 0) {
            gh1[j]           = red[0][0] + red[1][0] + red[2][0] + red[3][0] + bh_r;
            gh1[j + HID]     = red[0][1] + red[1][1] + red[2][1] + red[3][1] + bh_z;
            gh1[j + 2 * HID] = red[0][2] + red[1][2] + red[2][2] + red[3][2] + bh_n;
        }
    }
}

// k2: gi1 = w_ih1 @ h0 + b_ih1; combine with gh1 -> h1
__global__ __launch_bounds__(256) void k2(
    const float* __restrict__ h_in,
    const float* __restrict__ w_ih1,
    const float* __restrict__ b_ih1,
    const float* __restrict__ gh1,
    float* __restrict__ out)
{
    const int tid  = threadIdx.x;
    const int lane = tid & 63;
    const int wv   = tid >> 6;
    const int j    = blockIdx.x;
    __shared__ float red[4][3];

    // prefetch epilogue scalars
    const float bi_r = b_ih1[j];
    const float bi_z = b_ih1[j + HID];
    const float bi_n = b_ih1[j + 2 * HID];
    const float g_r  = gh1[j];
    const float g_z  = gh1[j + HID];
    const float g_n  = gh1[j + 2 * HID];
    const float hprev = h_in[HID + j];

    const float4* hv  = (const float4*)(out + NV);                    // h0 from k1
    const float4* wi0 = (const float4*)(w_ih1 + (size_t)j * HID);
    const float4* wi1 = (const float4*)(w_ih1 + (size_t)(j + HID) * HID);
    const float4* wi2 = (const float4*)(w_ih1 + (size_t)(j + 2 * HID) * HID);

    float4 x0 = hv[tid];
    float4 x1 = hv[tid + 256];
    float4 a0 = wi0[tid];
    float4 a1 = wi0[tid + 256];
    float4 b0 = wi1[tid];
    float4 b1 = wi1[tid + 256];
    float4 d0 = wi2[tid];
    float4 d1 = wi2[tid + 256];

    float s0 = dot4(a0, x0) + dot4(a1, x1);
    float s1 = dot4(b0, x0) + dot4(b1, x1);
    float s2 = dot4(d0, x0) + dot4(d1, x1);

    s0 = wred(s0); s1 = wred(s1); s2 = wred(s2);
    if (lane == 0) { red[wv][0] = s0; red[wv][1] = s1; red[wv][2] = s2; }
    __syncthreads();
    if (tid == 0) {
        float ir  = red[0][0] + red[1][0] + red[2][0] + red[3][0] + bi_r;
        float iz  = red[0][1] + red[1][1] + red[2][1] + red[3][1] + bi_z;
        float inn = red[0][2] + red[1][2] + red[2][2] + red[3][2] + bi_n;
        float r = sig(ir + g_r);
        float z = sig(iz + g_z);
        float n = tanhf(inn + r * g_n);
        out[NV + HID + j] = (1.0f - z) * n + z * hprev;
    }
}

// k3: logits = w_head @ h1 + b_head; softmax -> probs
__global__ __launch_bounds__(256) void k3(
    const float* __restrict__ w_head,
    const float* __restrict__ b_head,
    float* __restrict__ out)
{
    const int tid = threadIdx.x;
    const int row = tid >> 4;   // 0..15
    const int sub = tid & 15;
    const float bh = b_head[row];
    const float4* hv = (const float4*)(out + NV + HID);               // h1 from k2
    const float4* w  = (const float4*)(w_head + (size_t)row * HID);

    float s = 0.f;
    // 512 float4 per row / 16 subs = 32 chunks; unroll 4 for ILP
#pragma unroll 4
    for (int c = sub; c < HID / 4; c += 16) {
        float4 x = hv[c];
        float4 a = w[c];
        s += dot4(a, x);
    }
#pragma unroll
    for (int o = 8; o >= 1; o >>= 1) s += __shfl_down(s, o, 16);

    __shared__ float logits[NV];
    if (sub == 0) logits[row] = s + bh;
    __syncthreads();
    if (tid == 0) {
        float m = logits[0];
#pragma unroll
        for (int i = 1; i < NV; ++i) m = fmaxf(m, logits[i]);
        float ex[NV]; float den = 0.f;
#pragma unroll
        for (int i = 0; i < NV; ++i) { ex[i] = __expf(logits[i] - m); den += ex[i]; }
        float inv = 1.0f / den;
#pragma unroll
        for (int i = 0; i < NV; ++i) out[i] = ex[i] * inv;
    }
}

extern "C" void kernel_launch(void* const* d_in, const int* in_sizes, int n_in,
                              void* d_out, int out_size, void* d_ws, size_t ws_size,
                              hipStream_t stream) {
    const int*   x      = (const int*)  d_in[0];
    const float* h_in   = (const float*)d_in[1];
    const float* emb    = (const float*)d_in[2];
    const float* w_ih0  = (const float*)d_in[3];
    const float* w_hh0  = (const float*)d_in[4];
    const float* b_ih0  = (const float*)d_in[5];
    const float* b_hh0  = (const float*)d_in[6];
    const float* w_ih1  = (const float*)d_in[7];
    const float* w_hh1  = (const float*)d_in[8];
    const float* b_ih1  = (const float*)d_in[9];
    const float* b_hh1  = (const float*)d_in[10];
    const float* w_head = (const float*)d_in[11];
    const float* b_head = (const float*)d_in[12];
    float* out = (float*)d_out;
    float* gh1 = (float*)d_ws;  // 6144 floats

    k1<<<2 * HID, 256, 0, stream>>>(x, h_in, emb, w_ih0, w_hh0, b_ih0, b_hh0,
                                    w_hh1, b_hh1, out, gh1);
    k2<<<HID, 256, 0, stream>>>(h_in, w_ih1, b_ih1, gh1, out);
    k3<<<1, 256, 0, stream>>>(w_head, b_head, out);
}